// Round 1
// 1051.481 us; speedup vs baseline: 1.0500x; 1.0500x over previous
//
#include <hip/hip_runtime.h>
#include <hip/hip_bf16.h>
#include <stdint.h>

#define B_    128
#define F_    4
#define V_    2048
#define D_    4096
#define DW    64      // D/64 bit-words per (b,f) row
#define VW    32      // V/64 bit-words per d column
#define ITERS 20
#define NKT   16      // K tiles of 128 over V=2048

typedef _Float16 half8 __attribute__((ext_vector_type(8)));
typedef float   floatx4 __attribute__((ext_vector_type(4)));

// ------------------------------------------------------------------
// Pack sign bits of float array (+-1.0 exactly) into the bitstream.
// 16 floats per thread (4x float4), 16-bit mask -> 2-byte store that
// lands exactly at bits [16t, 16t+15] of the u64 word stream.
// ------------------------------------------------------------------
__global__ __launch_bounds__(256) void k_pack(const float* __restrict__ x,
                                              uint64_t* __restrict__ bits, int n) {
    int t = blockIdx.x * blockDim.x + threadIdx.x;
    if (t * 16 >= n) return;
    const float4* p = (const float4*)x + (size_t)t * 4;
    uint32_t m = 0;
    #pragma unroll
    for (int j = 0; j < 4; ++j) {
        float4 v = p[j];
        m |= (__float_as_uint(v.x) >> 31) << (4 * j + 0);
        m |= (__float_as_uint(v.y) >> 31) << (4 * j + 1);
        m |= (__float_as_uint(v.z) >> 31) << (4 * j + 2);
        m |= (__float_as_uint(v.w) >> 31) << (4 * j + 3);
    }
    ((unsigned short*)bits)[t] = (unsigned short)m;
}

// ------------------------------------------------------------------
// Transpose cb_bits[f][v][dwords] -> cbT[f][d][vwords] (bit v of word).
// grid (vw=32, dwg=16, f=4), block 256 (4 waves, wave = one dw).
// ------------------------------------------------------------------
__global__ void k_packT(const uint64_t* __restrict__ cb_bits,
                        uint64_t* __restrict__ cbT) {
    int vw = blockIdx.x, dwg = blockIdx.y, f = blockIdx.z;
    int lane = threadIdx.x & 63;
    int dw = dwg * 4 + (threadIdx.x >> 6);
    uint64_t w = cb_bits[((size_t)f * V_ + vw * 64 + lane) * DW + dw];
    uint64_t r = 0;
    for (int d2 = 0; d2 < 64; ++d2) {
        uint64_t m = __ballot((unsigned)((w >> d2) & 1));
        if (lane == d2) r = m;
    }
    cbT[((size_t)f * D_ + dw * 64 + lane) * VW + vw] = r;
}

// ------------------------------------------------------------------
// sim[b,f,v] = 2048 - popcount(new_est ^ cb_row), exact fp16.
// new_est bits = in ^ e0^e1^e2^e3 ^ ef.
// grid (vt=8, bt=32, f=4) = 1024 blocks (4/CU, 16 waves/CU), 4 b/block.
// 32-B cb loads, unroll 2 -> multiple loads in flight.
// ------------------------------------------------------------------
__global__ __launch_bounds__(256) void k_sim(
        const uint64_t* __restrict__ cb_bits,
        const uint64_t* __restrict__ in_bits,
        const uint64_t* __restrict__ est_bits,
        _Float16* __restrict__ simf,
        const int* __restrict__ flags, int iter) {
    if (iter > 0 && flags[iter - 1] == 0) return;
    int vt = blockIdx.x, bt = blockIdx.y, f = blockIdx.z;
    int tid = threadIdx.x;
    __shared__ __align__(16) uint64_t nb[4][DW];
    {
        int bl = tid >> 6, w = tid & 63;          // 256 = 4 b * 64 words
        int b = bt * 4 + bl;
        const uint64_t* e = est_bits + (size_t)b * F_ * DW;
        nb[bl][w] = in_bits[(size_t)b * DW + w] ^ e[0 * DW + w] ^ e[1 * DW + w]
                  ^ e[2 * DW + w] ^ e[3 * DW + w] ^ e[(size_t)f * DW + w];
    }
    __syncthreads();
    int v = vt * 256 + tid;
    int acc[4];
    #pragma unroll
    for (int bl = 0; bl < 4; ++bl) acc[bl] = 2048;
    const uint64_t* cbrow = cb_bits + ((size_t)f * V_ + v) * DW;
    #pragma unroll 2
    for (int w = 0; w < DW; w += 4) {
        ulonglong4 c4 = *(const ulonglong4*)&cbrow[w];
        #pragma unroll
        for (int bl = 0; bl < 4; ++bl) {
            const uint64_t* nrow = &nb[bl][w];
            acc[bl] -= __popcll(nrow[0] ^ c4.x) + __popcll(nrow[1] ^ c4.y)
                     + __popcll(nrow[2] ^ c4.z) + __popcll(nrow[3] ^ c4.w);
        }
    }
    #pragma unroll
    for (int bl = 0; bl < 4; ++bl)
        simf[((size_t)f * B_ + bt * 4 + bl) * V_ + v] = (_Float16)acc[bl];
}

// ------------------------------------------------------------------
// C[b,d] = sum_v sim[b,v] * (+-1 from cbT bits); hardsign -> est_bits.
// BM=64 BN=64 BK=128; grid (nt=64, mt=2, f=4)=512 blocks, 256 thr.
// Wave tile 32m x 32n via 16x16x32 f16 MFMA (layout HW-verified R1).
// B bits preloaded to LDS once (XOR-swizzled); bytes decoded in regs
// via multiply bit-spread (bits 0..3 -> f16 signs at 15/31/47/63).
// A tile prefetched to regs, XOR-swizzled LDS, conflict-free b128.
// ------------------------------------------------------------------
__global__ __launch_bounds__(256) void k_gemm(
        const _Float16* __restrict__ simf,
        const uint64_t* __restrict__ cbT,
        uint64_t* __restrict__ est_bits,
        int* __restrict__ flags, int iter) {
    if (iter > 0 && flags[iter - 1] == 0) return;
    int nt = blockIdx.x, mt = blockIdx.y, f = blockIdx.z;
    int m0 = mt * 64, n0 = nt * 64;
    int tid = threadIdx.x;
    int lane = tid & 63, wave = tid >> 6;
    int lrow = lane & 15, lq = lane >> 4;
    int wm = wave & 1, wn = wave >> 1;

    __shared__ __align__(16) uint64_t Bb[64 * VW];      // 16 KB, swizzled chunks
    __shared__ __align__(16) _Float16 As[64 * 128];     // 16 KB, swizzled chunks
    __shared__ int bd;
    if (tid == 0) bd = 0;

    // preload B bit-panel: 64 d-rows x 32 vwords, chunk(16B) cw' = cw ^ (dloc&15)
    const uint64_t* bsrc = cbT + ((size_t)f * D_ + n0) * VW;
    #pragma unroll
    for (int p = 0; p < 4; ++p) {
        int chunk = p * 256 + tid;                 // 1024 chunks
        int dloc = chunk >> 4, cw = chunk & 15;
        ulonglong2 val = *(const ulonglong2*)&bsrc[dloc * VW + cw * 2];
        *(ulonglong2*)&Bb[dloc * VW + ((cw ^ (dloc & 15)) * 2)] = val;
    }

    const _Float16* Ab = simf + (size_t)f * B_ * V_ + (size_t)m0 * V_;
    int arow = tid >> 4, acol = tid & 15;          // 16 rows x 16 chunks per pass
    half8 areg[4];
    #pragma unroll
    for (int p = 0; p < 4; ++p)
        areg[p] = *(const half8*)&Ab[(size_t)(p * 16 + arow) * V_ + acol * 8];

    floatx4 acc[2][2] = {};

    const uint64_t SPREAD = 0x1000200040008000ull;  // bit b -> pos 15+16b
    const uint64_t SMASK  = 0x8000800080008000ull;
    const uint64_t PONE   = 0x3C003C003C003C00ull;  // f16 +1.0 x4

    #pragma unroll 1
    for (int kt = 0; kt < NKT; ++kt) {
        __syncthreads();
        #pragma unroll
        for (int p = 0; p < 4; ++p)
            *(half8*)&As[(p * 16 + arow) * 128 + ((acol ^ arow) * 8)] = areg[p];
        if (kt + 1 < NKT) {
            #pragma unroll
            for (int p = 0; p < 4; ++p)   // prefetch next A tile (in flight over compute)
                areg[p] = *(const half8*)&Ab[(size_t)(p * 16 + arow) * V_ + (kt + 1) * 128 + acol * 8];
        }
        __syncthreads();

        ulonglong2 bw[2];
        #pragma unroll
        for (int nt2 = 0; nt2 < 2; ++nt2) {
            int dloc = wn * 32 + nt2 * 16 + lrow;
            bw[nt2] = *(const ulonglong2*)&Bb[dloc * VW + ((kt ^ (dloc & 15)) * 2)];
        }
        #pragma unroll
        for (int ks = 0; ks < 4; ++ks) {
            half8 af[2];
            #pragma unroll
            for (int mt2 = 0; mt2 < 2; ++mt2) {
                int row = wm * 32 + mt2 * 16 + lrow;
                af[mt2] = *(const half8*)&As[row * 128 + (((ks * 4 + lq) ^ lrow) * 8)];
            }
            half8 bfrag[2];
            #pragma unroll
            for (int nt2 = 0; nt2 < 2; ++nt2) {
                uint64_t w = (ks < 2) ? bw[nt2].x : bw[nt2].y;
                uint32_t byte = (uint32_t)(w >> ((((ks & 1) * 4 + lq)) * 8)) & 0xFFu;
                union { uint64_t q[2]; half8 h; } bu;
                bu.q[0] = (((uint64_t)(byte & 0xFu) * SPREAD) & SMASK) ^ PONE;
                bu.q[1] = (((uint64_t)(byte >> 4)   * SPREAD) & SMASK) ^ PONE;
                bfrag[nt2] = bu.h;
            }
            #pragma unroll
            for (int mt2 = 0; mt2 < 2; ++mt2)
                #pragma unroll
                for (int nt2 = 0; nt2 < 2; ++nt2)
                    acc[mt2][nt2] = __builtin_amdgcn_mfma_f32_16x16x32_f16(
                        af[mt2], bfrag[nt2], acc[mt2][nt2], 0, 0, 0);
        }
    }

    // epilogue: hardsign -> LDS bytes -> bit-pack 64-bit word per row
    __syncthreads();
    unsigned char* S = (unsigned char*)As;
    #pragma unroll
    for (int mt2 = 0; mt2 < 2; ++mt2)
        #pragma unroll
        for (int nt2 = 0; nt2 < 2; ++nt2)
            #pragma unroll
            for (int r = 0; r < 4; ++r) {
                int row = wm * 32 + mt2 * 16 + lq * 4 + r;   // C/D: row = quad*4+reg
                int col = wn * 32 + nt2 * 16 + lrow;         // col = lane&15
                S[row * 64 + col] = (acc[mt2][nt2][r] < 0.0f) ? 1 : 0;  // sign(0)=+1
            }
    __syncthreads();
    if (tid < 64) {
        const uint64_t* Sw = (const uint64_t*)S;
        uint64_t m = 0;
        #pragma unroll
        for (int j = 0; j < 8; ++j) {
            uint64_t w = Sw[tid * 8 + j];                    // 8 bytes of 0/1
            m |= ((w * 0x0102040810204080ull) >> 56) << (8 * j);  // exact bit-gather
        }
        size_t widx = ((size_t)(m0 + tid) * F_ + f) * DW + nt;
        uint64_t old = est_bits[widx];
        est_bits[widx] = m;
        if (old != m) atomicOr(&bd, 1);
    }
    __syncthreads();
    if (tid == 0 && bd) atomicOr(&flags[iter], 1);
}

// ------------------------------------------------------------------
// argmax_v |sim|: key = (|2048-pc|<<11) | (2047-v), atomicMax.
// grid (vt=8, bg=8, f=4) = 256 blocks; 16 b staged per block.
// ------------------------------------------------------------------
__global__ __launch_bounds__(256) void k_argmax(
        const uint64_t* __restrict__ cb_bits,
        const uint64_t* __restrict__ est_bits,
        int* __restrict__ keys) {
    int vt = blockIdx.x, bg = blockIdx.y, f = blockIdx.z;
    int tid = threadIdx.x, lane = tid & 63;
    __shared__ __align__(16) uint64_t eb[16][DW];
    #pragma unroll
    for (int j = 0; j < 4; ++j) {
        int idx = tid + j * 256;
        int bl = idx >> 6, w = idx & 63;
        eb[bl][w] = est_bits[((size_t)(bg * 16 + bl) * F_ + f) * DW + w];
    }
    __syncthreads();
    int v = vt * 256 + tid;
    const uint64_t* cbrow = cb_bits + ((size_t)f * V_ + v) * DW;
    int pc[16];
    #pragma unroll
    for (int bl = 0; bl < 16; ++bl) pc[bl] = 0;
    for (int w = 0; w < DW; w += 2) {
        ulonglong2 c2 = *(const ulonglong2*)&cbrow[w];
        #pragma unroll
        for (int bl = 0; bl < 16; ++bl) {
            ulonglong2 e2 = *(const ulonglong2*)&eb[bl][w];
            pc[bl] += __popcll(e2.x ^ c2.x) + __popcll(e2.y ^ c2.y);
        }
    }
    int key[16];
    #pragma unroll
    for (int bl = 0; bl < 16; ++bl) {
        int m = 2048 - pc[bl]; if (m < 0) m = -m;
        key[bl] = (m << 11) | (2047 - v);
    }
    #pragma unroll
    for (int s = 1; s < 64; s <<= 1)
        #pragma unroll
        for (int bl = 0; bl < 16; ++bl) {
            int o = __shfl_xor(key[bl], s, 64);
            if (o > key[bl]) key[bl] = o;
        }
    if (lane == 0)
        for (int bl = 0; bl < 16; ++bl)
            atomicMax(&keys[(size_t)(bg * 16 + bl) * F_ + f], key[bl]);
}

__global__ void k_final(const int* __restrict__ keys, const int* __restrict__ flags,
                        int* __restrict__ out) {
    int tid = blockIdx.x * blockDim.x + threadIdx.x;
    if (tid < B_ * F_) out[tid] = 2047 - (keys[tid] & 0x7FF);
    if (tid == 0) {
        int k = ITERS - 1;
        for (int i = 0; i < ITERS; ++i) if (flags[i] == 0) { k = i; break; }
        out[B_ * F_] = k;
    }
}

// ------------------------------------------------------------------
extern "C" void kernel_launch(void* const* d_in, const int* in_sizes, int n_in,
                              void* d_out, int out_size, void* d_ws, size_t ws_size,
                              hipStream_t stream) {
    const float* inputs = (const float*)d_in[0];   // (B, D)
    const float* inite  = (const float*)d_in[1];   // (B, F, D)
    const float* cb     = (const float*)d_in[2];   // (F, V, D)
    int* out = (int*)d_out;                        // 512 outcome + 1 k

    char* ws = (char*)d_ws;
    uint64_t* cb_bits  = (uint64_t*)ws;  ws += (size_t)F_ * V_ * DW * 8;   // 4 MiB
    uint64_t* cbT_bits = (uint64_t*)ws;  ws += (size_t)F_ * D_ * VW * 8;   // 4 MiB
    uint64_t* est_bits = (uint64_t*)ws;  ws += (size_t)B_ * F_ * DW * 8;   // 256 KiB
    uint64_t* in_bits  = (uint64_t*)ws;  ws += (size_t)B_ * DW * 8;        // 64 KiB
    _Float16* simf     = (_Float16*)ws;  ws += (size_t)F_ * B_ * V_ * 2;   // 2 MiB
    int*      flags    = (int*)ws;       ws += 32 * 4;
    int*      keys     = (int*)ws;       ws += B_ * F_ * 4;

    hipMemsetAsync(flags, 0, (32 + B_ * F_) * sizeof(int), stream);
    k_pack<<<(F_ * V_ * D_) / 4096, 256, 0, stream>>>(cb,     cb_bits,  F_ * V_ * D_);
    k_pack<<<(B_ * F_ * D_) / 4096, 256, 0, stream>>>(inite,  est_bits, B_ * F_ * D_);
    k_pack<<<(B_ * D_) / 4096,      256, 0, stream>>>(inputs, in_bits,  B_ * D_);
    k_packT<<<dim3(32, 16, 4), 256, 0, stream>>>(cb_bits, cbT_bits);

    for (int i = 0; i < ITERS; ++i) {
        k_sim<<<dim3(8, 32, 4), 256, 0, stream>>>(cb_bits, in_bits, est_bits, simf, flags, i);
        k_gemm<<<dim3(64, 2, 4), 256, 0, stream>>>(simf, cbT_bits, est_bits, flags, i);
    }
    k_argmax<<<dim3(8, 8, 4), 256, 0, stream>>>(cb_bits, est_bits, keys);
    k_final<<<2, 256, 0, stream>>>(keys, flags, out);
}

// Round 2
// 1004.983 us; speedup vs baseline: 1.0986x; 1.0463x over previous
//
#include <hip/hip_runtime.h>
#include <hip/hip_bf16.h>
#include <stdint.h>

#define B_    128
#define F_    4
#define V_    2048
#define D_    4096
#define DW    64      // D/64 bit-words per (b,f) row
#define VW    32      // V/64 bit-words per d column
#define ITERS 20
#define NKT   16      // K tiles of 128 over V=2048

typedef _Float16 half8 __attribute__((ext_vector_type(8)));
typedef float   floatx4 __attribute__((ext_vector_type(4)));

// ------------------------------------------------------------------
// Pack sign bits of float array (+-1.0 exactly) into the bitstream.
// 16 floats per thread (4x float4), 16-bit mask -> 2-byte store.
// ------------------------------------------------------------------
__global__ __launch_bounds__(256) void k_pack(const float* __restrict__ x,
                                              uint64_t* __restrict__ bits, int n) {
    int t = blockIdx.x * blockDim.x + threadIdx.x;
    if (t * 16 >= n) return;
    const float4* p = (const float4*)x + (size_t)t * 4;
    uint32_t m = 0;
    #pragma unroll
    for (int j = 0; j < 4; ++j) {
        float4 v = p[j];
        m |= (__float_as_uint(v.x) >> 31) << (4 * j + 0);
        m |= (__float_as_uint(v.y) >> 31) << (4 * j + 1);
        m |= (__float_as_uint(v.z) >> 31) << (4 * j + 2);
        m |= (__float_as_uint(v.w) >> 31) << (4 * j + 3);
    }
    ((unsigned short*)bits)[t] = (unsigned short)m;
}

// ------------------------------------------------------------------
// Transpose cb_bits[f][v][dwords] -> cbT[f][d][vwords] (bit v of word).
// ------------------------------------------------------------------
__global__ void k_packT(const uint64_t* __restrict__ cb_bits,
                        uint64_t* __restrict__ cbT) {
    int vw = blockIdx.x, dwg = blockIdx.y, f = blockIdx.z;
    int lane = threadIdx.x & 63;
    int dw = dwg * 4 + (threadIdx.x >> 6);
    uint64_t w = cb_bits[((size_t)f * V_ + vw * 64 + lane) * DW + dw];
    uint64_t r = 0;
    for (int d2 = 0; d2 < 64; ++d2) {
        uint64_t m = __ballot((unsigned)((w >> d2) & 1));
        if (lane == d2) r = m;
    }
    cbT[((size_t)f * D_ + dw * 64 + lane) * VW + vw] = r;
}

// ------------------------------------------------------------------
// sim[b,f,v] = 2048 - popcount(new_est ^ cb_row), exact fp16.
// LDS-tiled bit-GEMM: per block stage cb tile (64 v-rows, 32 KB) and
// nb tile (64 b-rows, 32 KB) with coalesced 16-B chunk loads,
// chunk-XOR-swizzled (ch ^= row&7) so compute-phase ds_read_b128 at
// row-stride 512 B is conflict-free. Thread = 4b x 4v register tile,
// rows interleaved stride-16 so swizzle classes span 8 banks-groups.
// grid (vt=32, bt=2, f=4) = 256 blocks, 256 thr.
// ------------------------------------------------------------------
__global__ __launch_bounds__(256) void k_sim(
        const uint64_t* __restrict__ cb_bits,
        const uint64_t* __restrict__ in_bits,
        const uint64_t* __restrict__ est_bits,
        _Float16* __restrict__ simf,
        const int* __restrict__ flags, int iter) {
    if (iter > 0 && flags[iter - 1] == 0) return;
    int vt = blockIdx.x, bt = blockIdx.y, f = blockIdx.z;
    int v0 = vt * 64, b0 = bt * 64;
    int tid = threadIdx.x;

    __shared__ __align__(16) ulonglong2 CB2[64 * 32];   // 32 KB
    __shared__ __align__(16) ulonglong2 NB2[64 * 32];   // 32 KB

    // stage cb tile: 64 rows x 32 chunks, coalesced, swizzled dest
    #pragma unroll
    for (int it = 0; it < 8; ++it) {
        int cq = it * 256 + tid;
        int r = cq >> 5, ch = cq & 31;
        const ulonglong2* src = (const ulonglong2*)(cb_bits + ((size_t)f * V_ + v0 + r) * DW);
        CB2[r * 32 + (ch ^ (r & 7))] = src[ch];
    }
    // stage nb tile: nb = in ^ e0^e1^e2^e3 ^ e[f]
    #pragma unroll
    for (int it = 0; it < 8; ++it) {
        int cq = it * 256 + tid;
        int r = cq >> 5, ch = cq & 31;
        int b = b0 + r;
        const ulonglong2* iv = (const ulonglong2*)(in_bits + (size_t)b * DW);
        const uint64_t* eb = est_bits + (size_t)b * F_ * DW;
        ulonglong2 i2 = iv[ch];
        ulonglong2 e0 = ((const ulonglong2*)(eb + 0 * DW))[ch];
        ulonglong2 e1 = ((const ulonglong2*)(eb + 1 * DW))[ch];
        ulonglong2 e2 = ((const ulonglong2*)(eb + 2 * DW))[ch];
        ulonglong2 e3 = ((const ulonglong2*)(eb + 3 * DW))[ch];
        ulonglong2 es = e0;
        if (f == 1) es = e1; else if (f == 2) es = e2; else if (f == 3) es = e3;
        ulonglong2 val;
        val.x = i2.x ^ e0.x ^ e1.x ^ e2.x ^ e3.x ^ es.x;
        val.y = i2.y ^ e0.y ^ e1.y ^ e2.y ^ e3.y ^ es.y;
        NB2[r * 32 + (ch ^ (r & 7))] = val;
    }
    __syncthreads();

    int vv = tid & 15, bb = tid >> 4;
    int svz = vv & 7, sbz = bb & 7;
    int pc[4][4];
    #pragma unroll
    for (int j = 0; j < 4; ++j)
        #pragma unroll
        for (int i = 0; i < 4; ++i) pc[j][i] = 0;

    #pragma unroll 4
    for (int ch = 0; ch < 32; ++ch) {
        ulonglong2 c[4], n[4];
        #pragma unroll
        for (int i = 0; i < 4; ++i)
            c[i] = CB2[(vv + 16 * i) * 32 + (ch ^ svz)];
        #pragma unroll
        for (int j = 0; j < 4; ++j)
            n[j] = NB2[(bb + 16 * j) * 32 + (ch ^ sbz)];
        #pragma unroll
        for (int j = 0; j < 4; ++j)
            #pragma unroll
            for (int i = 0; i < 4; ++i)
                pc[j][i] += __popcll(n[j].x ^ c[i].x) + __popcll(n[j].y ^ c[i].y);
    }

    #pragma unroll
    for (int j = 0; j < 4; ++j) {
        int b = b0 + bb + 16 * j;
        #pragma unroll
        for (int i = 0; i < 4; ++i) {
            int v = v0 + vv + 16 * i;
            simf[((size_t)f * B_ + b) * V_ + v] = (_Float16)(2048 - pc[j][i]);
        }
    }
}

// ------------------------------------------------------------------
// C[b,d] = sum_v sim[b,v] * (+-1 from cbT bits); hardsign -> est_bits.
// BM=64 BN=64 BK=128; grid (nt=64, mt=2, f=4)=512 blocks, 256 thr.
// ------------------------------------------------------------------
__global__ __launch_bounds__(256) void k_gemm(
        const _Float16* __restrict__ simf,
        const uint64_t* __restrict__ cbT,
        uint64_t* __restrict__ est_bits,
        int* __restrict__ flags, int iter) {
    if (iter > 0 && flags[iter - 1] == 0) return;
    int nt = blockIdx.x, mt = blockIdx.y, f = blockIdx.z;
    int m0 = mt * 64, n0 = nt * 64;
    int tid = threadIdx.x;
    int lane = tid & 63, wave = tid >> 6;
    int lrow = lane & 15, lq = lane >> 4;
    int wm = wave & 1, wn = wave >> 1;

    __shared__ __align__(16) uint64_t Bb[64 * VW];      // 16 KB, swizzled chunks
    __shared__ __align__(16) _Float16 As[64 * 128];     // 16 KB, swizzled chunks
    __shared__ int bd;
    if (tid == 0) bd = 0;

    const uint64_t* bsrc = cbT + ((size_t)f * D_ + n0) * VW;
    #pragma unroll
    for (int p = 0; p < 4; ++p) {
        int chunk = p * 256 + tid;                 // 1024 chunks
        int dloc = chunk >> 4, cw = chunk & 15;
        ulonglong2 val = *(const ulonglong2*)&bsrc[dloc * VW + cw * 2];
        *(ulonglong2*)&Bb[dloc * VW + ((cw ^ (dloc & 15)) * 2)] = val;
    }

    const _Float16* Ab = simf + (size_t)f * B_ * V_ + (size_t)m0 * V_;
    int arow = tid >> 4, acol = tid & 15;
    half8 areg[4];
    #pragma unroll
    for (int p = 0; p < 4; ++p)
        areg[p] = *(const half8*)&Ab[(size_t)(p * 16 + arow) * V_ + acol * 8];

    floatx4 acc[2][2] = {};

    const uint64_t SPREAD = 0x1000200040008000ull;  // bit b -> pos 15+16b
    const uint64_t SMASK  = 0x8000800080008000ull;
    const uint64_t PONE   = 0x3C003C003C003C00ull;  // f16 +1.0 x4

    #pragma unroll 1
    for (int kt = 0; kt < NKT; ++kt) {
        __syncthreads();
        #pragma unroll
        for (int p = 0; p < 4; ++p)
            *(half8*)&As[(p * 16 + arow) * 128 + ((acol ^ arow) * 8)] = areg[p];
        if (kt + 1 < NKT) {
            #pragma unroll
            for (int p = 0; p < 4; ++p)
                areg[p] = *(const half8*)&Ab[(size_t)(p * 16 + arow) * V_ + (kt + 1) * 128 + acol * 8];
        }
        __syncthreads();

        ulonglong2 bw[2];
        #pragma unroll
        for (int nt2 = 0; nt2 < 2; ++nt2) {
            int dloc = wn * 32 + nt2 * 16 + lrow;
            bw[nt2] = *(const ulonglong2*)&Bb[dloc * VW + ((kt ^ (dloc & 15)) * 2)];
        }
        #pragma unroll
        for (int ks = 0; ks < 4; ++ks) {
            half8 af[2];
            #pragma unroll
            for (int mt2 = 0; mt2 < 2; ++mt2) {
                int row = wm * 32 + mt2 * 16 + lrow;
                af[mt2] = *(const half8*)&As[row * 128 + (((ks * 4 + lq) ^ lrow) * 8)];
            }
            half8 bfrag[2];
            #pragma unroll
            for (int nt2 = 0; nt2 < 2; ++nt2) {
                uint64_t w = (ks < 2) ? bw[nt2].x : bw[nt2].y;
                uint32_t byte = (uint32_t)(w >> ((((ks & 1) * 4 + lq)) * 8)) & 0xFFu;
                union { uint64_t q[2]; half8 h; } bu;
                bu.q[0] = (((uint64_t)(byte & 0xFu) * SPREAD) & SMASK) ^ PONE;
                bu.q[1] = (((uint64_t)(byte >> 4)   * SPREAD) & SMASK) ^ PONE;
                bfrag[nt2] = bu.h;
            }
            #pragma unroll
            for (int mt2 = 0; mt2 < 2; ++mt2)
                #pragma unroll
                for (int nt2 = 0; nt2 < 2; ++nt2)
                    acc[mt2][nt2] = __builtin_amdgcn_mfma_f32_16x16x32_f16(
                        af[mt2], bfrag[nt2], acc[mt2][nt2], 0, 0, 0);
        }
    }

    // epilogue: hardsign -> LDS bytes -> bit-pack 64-bit word per row
    __syncthreads();
    unsigned char* S = (unsigned char*)As;
    #pragma unroll
    for (int mt2 = 0; mt2 < 2; ++mt2)
        #pragma unroll
        for (int nt2 = 0; nt2 < 2; ++nt2)
            #pragma unroll
            for (int r = 0; r < 4; ++r) {
                int row = wm * 32 + mt2 * 16 + lq * 4 + r;
                int col = wn * 32 + nt2 * 16 + lrow;
                S[row * 64 + col] = (acc[mt2][nt2][r] < 0.0f) ? 1 : 0;
            }
    __syncthreads();
    if (tid < 64) {
        const uint64_t* Sw = (const uint64_t*)S;
        uint64_t m = 0;
        #pragma unroll
        for (int j = 0; j < 8; ++j) {
            uint64_t w = Sw[tid * 8 + j];
            m |= ((w * 0x0102040810204080ull) >> 56) << (8 * j);
        }
        size_t widx = ((size_t)(m0 + tid) * F_ + f) * DW + nt;
        uint64_t old = est_bits[widx];
        est_bits[widx] = m;
        if (old != m) atomicOr(&bd, 1);
    }
    __syncthreads();
    if (tid == 0 && bd) atomicOr(&flags[iter], 1);
}

// ------------------------------------------------------------------
// argmax_v |sim|: key = (|2048-pc|<<11) | (2047-v), atomicMax.
// LDS-tiled like k_sim: stage est for ALL 128 b (64 KB) + 32-v cb
// tile (16 KB), swizzled. Thread = 8b x 2v register tile.
// grid (vt=64, f=4) = 256 blocks, 256 thr.
// ------------------------------------------------------------------
__global__ __launch_bounds__(256) void k_argmax(
        const uint64_t* __restrict__ cb_bits,
        const uint64_t* __restrict__ est_bits,
        int* __restrict__ keys) {
    int vt = blockIdx.x, f = blockIdx.y;
    int v0 = vt * 32;
    int tid = threadIdx.x;

    __shared__ __align__(16) ulonglong2 EB2[128 * 32];  // 64 KB
    __shared__ __align__(16) ulonglong2 CBa[32 * 32];   // 16 KB

    #pragma unroll
    for (int it = 0; it < 16; ++it) {
        int cq = it * 256 + tid;                 // 4096 chunks
        int r = cq >> 5, ch = cq & 31;
        const ulonglong2* src = (const ulonglong2*)(est_bits + ((size_t)r * F_ + f) * DW);
        EB2[r * 32 + (ch ^ (r & 7))] = src[ch];
    }
    #pragma unroll
    for (int it = 0; it < 4; ++it) {
        int cq = it * 256 + tid;                 // 1024 chunks
        int r = cq >> 5, ch = cq & 31;
        const ulonglong2* src = (const ulonglong2*)(cb_bits + ((size_t)f * V_ + v0 + r) * DW);
        CBa[r * 32 + (ch ^ (r & 7))] = src[ch];
    }
    __syncthreads();

    int vv = tid & 15, bb = tid >> 4;
    int svz = vv & 7, sbz = bb & 7;
    int pc[8][2];
    #pragma unroll
    for (int j = 0; j < 8; ++j) { pc[j][0] = 0; pc[j][1] = 0; }

    #pragma unroll 4
    for (int ch = 0; ch < 32; ++ch) {
        ulonglong2 c[2], n[8];
        #pragma unroll
        for (int i = 0; i < 2; ++i)
            c[i] = CBa[(vv + 16 * i) * 32 + (ch ^ svz)];
        #pragma unroll
        for (int j = 0; j < 8; ++j)
            n[j] = EB2[(bb + 16 * j) * 32 + (ch ^ sbz)];
        #pragma unroll
        for (int j = 0; j < 8; ++j)
            #pragma unroll
            for (int i = 0; i < 2; ++i)
                pc[j][i] += __popcll(n[j].x ^ c[i].x) + __popcll(n[j].y ^ c[i].y);
    }

    #pragma unroll
    for (int j = 0; j < 8; ++j) {
        int kj = 0x80000000;
        #pragma unroll
        for (int i = 0; i < 2; ++i) {
            int v = v0 + vv + 16 * i;
            int m = 2048 - pc[j][i]; if (m < 0) m = -m;
            int key = (m << 11) | (2047 - v);
            if (key > kj) kj = key;
        }
        // reduce over vv (lanes within 16-group)
        #pragma unroll
        for (int s = 1; s < 16; s <<= 1) {
            int o = __shfl_xor(kj, s, 64);
            if (o > kj) kj = o;
        }
        if ((tid & 15) == 0)
            atomicMax(&keys[(size_t)(bb + 16 * j) * F_ + f], kj);
    }
}

__global__ void k_final(const int* __restrict__ keys, const int* __restrict__ flags,
                        int* __restrict__ out) {
    int tid = blockIdx.x * blockDim.x + threadIdx.x;
    if (tid < B_ * F_) out[tid] = 2047 - (keys[tid] & 0x7FF);
    if (tid == 0) {
        int k = ITERS - 1;
        for (int i = 0; i < ITERS; ++i) if (flags[i] == 0) { k = i; break; }
        out[B_ * F_] = k;
    }
}

// ------------------------------------------------------------------
extern "C" void kernel_launch(void* const* d_in, const int* in_sizes, int n_in,
                              void* d_out, int out_size, void* d_ws, size_t ws_size,
                              hipStream_t stream) {
    const float* inputs = (const float*)d_in[0];   // (B, D)
    const float* inite  = (const float*)d_in[1];   // (B, F, D)
    const float* cb     = (const float*)d_in[2];   // (F, V, D)
    int* out = (int*)d_out;                        // 512 outcome + 1 k

    char* ws = (char*)d_ws;
    uint64_t* cb_bits  = (uint64_t*)ws;  ws += (size_t)F_ * V_ * DW * 8;   // 4 MiB
    uint64_t* cbT_bits = (uint64_t*)ws;  ws += (size_t)F_ * D_ * VW * 8;   // 4 MiB
    uint64_t* est_bits = (uint64_t*)ws;  ws += (size_t)B_ * F_ * DW * 8;   // 256 KiB
    uint64_t* in_bits  = (uint64_t*)ws;  ws += (size_t)B_ * DW * 8;        // 64 KiB
    _Float16* simf     = (_Float16*)ws;  ws += (size_t)F_ * B_ * V_ * 2;   // 2 MiB
    int*      flags    = (int*)ws;       ws += 32 * 4;
    int*      keys     = (int*)ws;       ws += B_ * F_ * 4;

    hipMemsetAsync(flags, 0, (32 + B_ * F_) * sizeof(int), stream);
    k_pack<<<(F_ * V_ * D_) / 4096, 256, 0, stream>>>(cb,     cb_bits,  F_ * V_ * D_);
    k_pack<<<(B_ * F_ * D_) / 4096, 256, 0, stream>>>(inite,  est_bits, B_ * F_ * D_);
    k_pack<<<(B_ * D_) / 4096,      256, 0, stream>>>(inputs, in_bits,  B_ * D_);
    k_packT<<<dim3(32, 16, 4), 256, 0, stream>>>(cb_bits, cbT_bits);

    for (int i = 0; i < ITERS; ++i) {
        k_sim<<<dim3(32, 2, 4), 256, 0, stream>>>(cb_bits, in_bits, est_bits, simf, flags, i);
        k_gemm<<<dim3(64, 2, 4), 256, 0, stream>>>(simf, cbT_bits, est_bits, flags, i);
    }
    k_argmax<<<dim3(64, 4), 256, 0, stream>>>(cb_bits, est_bits, keys);
    k_final<<<2, 256, 0, stream>>>(keys, flags, out);
}